// Round 9
// baseline (593.259 us; speedup 1.0000x reference)
//
#include <hip/hip_runtime.h>
#include <math.h>

#define D_MODEL 1024
#define D_STATE 16
#define D_CONV  4
#define D_INNER 2048
#define DT_RANK 64
#define B_SZ    2
#define L_SEQ   2048
#define NROW    (B_SZ * L_SEQ)   // 4096

typedef __bf16 bf16x8 __attribute__((ext_vector_type(8)));
typedef float  f32x4  __attribute__((ext_vector_type(4)));
typedef unsigned short ushort8 __attribute__((ext_vector_type(8)));

__device__ __forceinline__ unsigned short f2bf(float f) {
    unsigned u = __float_as_uint(f);
    u += 0x7fff + ((u >> 16) & 1);       // RNE
    return (unsigned short)(u >> 16);
}
__device__ __forceinline__ float bf2f(unsigned short v) {
    return __uint_as_float((unsigned)v << 16);
}
__device__ __forceinline__ unsigned short f2h(float f) {
    _Float16 h = (_Float16)f;
    return *(unsigned short*)&h;
}
__device__ __forceinline__ float h2f(unsigned short u) {
    _Float16 h = *(_Float16*)&u;
    return (float)h;
}
__device__ __forceinline__ float softplus_f(float x) {
    return (x > 20.f) ? x : log1pf(__expf(x));
}

// ---------------------------------------------------------------------------
// Batched fp32 -> bf16 conversion: x, in_proj_w, dt_proj_w, out_proj_w,
// plus x_proj_w padded [96][2048] -> [128][2048].
// ---------------------------------------------------------------------------
#define S_X    (NROW * D_MODEL)                 // 4,194,304
#define S_IN   (2 * D_INNER * D_MODEL)          // 4,194,304
#define S_DT   (D_INNER * DT_RANK)              //   131,072
#define S_OUT  (D_MODEL * D_INNER)              // 2,097,152
#define S_TOT  (S_X + S_IN + S_DT + S_OUT)      // 10,616,832
#define S_PAD  (128 * 2048)                     //   262,144
#define S_ALL  (S_TOT + S_PAD)                  // 10,878,976

__global__ __launch_bounds__(256) void cvt_all(
    const float* __restrict__ x,   const float* __restrict__ inw,
    const float* __restrict__ dtw, const float* __restrict__ outw,
    const float* __restrict__ xpw,
    unsigned short* __restrict__ x_bf,   unsigned short* __restrict__ inw_bf,
    unsigned short* __restrict__ dtw_bf, unsigned short* __restrict__ outw_bf,
    unsigned short* __restrict__ xpw_bf)
{
    const int i = (blockIdx.x * 256 + threadIdx.x) * 4;
    if (i >= S_ALL) return;
    if (i >= S_TOT) {   // padded x_proj_w segment
        const int off = i - S_TOT;
        const int row = off >> 11;
        ushort4 o = make_ushort4(0, 0, 0, 0);
        if (row < 96) {
            const float4 v = *(const float4*)(xpw + (size_t)row * 2048 + (off & 2047));
            o.x = f2bf(v.x); o.y = f2bf(v.y); o.z = f2bf(v.z); o.w = f2bf(v.w);
        }
        *(ushort4*)(xpw_bf + off) = o;
        return;
    }
    const float* src; unsigned short* dst; int off;
    if (i < S_X)                    { src = x;    dst = x_bf;    off = i; }
    else if (i < S_X + S_IN)        { src = inw;  dst = inw_bf;  off = i - S_X; }
    else if (i < S_X + S_IN + S_DT) { src = dtw;  dst = dtw_bf;  off = i - S_X - S_IN; }
    else                            { src = outw; dst = outw_bf; off = i - S_X - S_IN - S_DT; }
    const float4 v = *(const float4*)(src + off);
    ushort4 o;
    o.x = f2bf(v.x); o.y = f2bf(v.y); o.z = f2bf(v.z); o.w = f2bf(v.w);
    *(ushort4*)(dst + off) = o;
}

// ---------------------------------------------------------------------------
// GEMM1 dedicated: xz = x_bf[4096,1024] @ inw_bf[4096,1024]^T -> bf16 [4096,4096].
// 128x128 tile, BK=64, 4 waves, 4x4 frags of 16x16x32.
// XCD swizzle: bid%8 = XCD (round-robin dispatch); each XCD owns a 16-row x
// 8-col block region -> per-XCD L2 footprint A 4MB + B 2MB (vs 16.8MB thrash).
// ---------------------------------------------------------------------------
__global__ __launch_bounds__(256, 4) void gemm_in(
    const unsigned short* __restrict__ A,
    const unsigned short* __restrict__ B,
    unsigned short* __restrict__ Cb)
{
    __shared__ unsigned short As[8][128 * 8];   // 16 KB
    __shared__ unsigned short Bs[8][128 * 8];   // 16 KB

    const int tid  = threadIdx.x;
    const int lane = tid & 63;
    const int w    = tid >> 6;
    const int wr   = w >> 1;
    const int wc   = w & 1;
    const int q    = lane >> 4;
    const int m    = lane & 15;

    // XCD-region swizzle over a 32x32 block grid
    const int bid = blockIdx.x;
    const int R   = bid & 7;          // region / XCD
    const int idx = bid >> 3;         // 0..127 within region
    const int by  = ((R >> 2) << 4) + (idx >> 3);   // 0..31
    const int bx  = ((R & 3) << 3) + (idx & 7);     // 0..31
    const int row0 = by * 128;
    const int col0 = bx * 128;

    f32x4 acc[4][4];
#pragma unroll
    for (int i = 0; i < 4; i++)
#pragma unroll
        for (int j = 0; j < 4; j++) acc[i][j] = (f32x4){0.f, 0.f, 0.f, 0.f};

    for (int k0 = 0; k0 < 1024; k0 += 64) {
#pragma unroll
        for (int i = 0; i < 4; i++) {
            const int c    = w * 4 + i;
            const int kb   = c >> 1;
            const int half = c & 1;
            const unsigned short* ga =
                A + (size_t)(row0 + half * 64 + lane) * 1024 + k0 + kb * 8;
            const unsigned short* gb =
                B + (size_t)(col0 + half * 64 + lane) * 1024 + k0 + kb * 8;
            __builtin_amdgcn_global_load_lds(
                (const __attribute__((address_space(1))) unsigned int*)ga,
                (__attribute__((address_space(3))) unsigned int*)&As[kb][half * 512],
                16, 0, 0);
            __builtin_amdgcn_global_load_lds(
                (const __attribute__((address_space(1))) unsigned int*)gb,
                (__attribute__((address_space(3))) unsigned int*)&Bs[kb][half * 512],
                16, 0, 0);
        }
        __syncthreads();

#pragma unroll
        for (int dep = 0; dep < 2; dep++) {
            bf16x8 af[4], bfr[4];
#pragma unroll
            for (int t = 0; t < 4; t++) {
                af[t]  = *(const bf16x8*)&As[dep * 4 + q][(wr * 64 + t * 16 + m) * 8];
                bfr[t] = *(const bf16x8*)&Bs[dep * 4 + q][(wc * 64 + t * 16 + m) * 8];
            }
#pragma unroll
            for (int mt = 0; mt < 4; mt++)
#pragma unroll
                for (int nt = 0; nt < 4; nt++)
                    acc[mt][nt] = __builtin_amdgcn_mfma_f32_16x16x32_bf16(
                        af[mt], bfr[nt], acc[mt][nt], 0, 0, 0);
        }
        __syncthreads();
    }

    // bf16 epilogue through LDS: two 64-row halves, reuse As
    unsigned short* ep = &As[0][0];
#pragma unroll
    for (int hh = 0; hh < 2; hh++) {
        if (wr == hh) {
#pragma unroll
            for (int mt = 0; mt < 4; mt++)
#pragma unroll
                for (int nt = 0; nt < 4; nt++)
#pragma unroll
                    for (int r = 0; r < 4; r++)
                        ep[(mt * 16 + q * 4 + r) * 128 + wc * 64 + nt * 16 + m] =
                            f2bf(acc[mt][nt][r]);
        }
        __syncthreads();
#pragma unroll
        for (int i = 0; i < 4; i++) {
            const int c    = i * 256 + tid;       // 0..1023
            const int rrow = c >> 4;
            const int off  = (c & 15) * 8;
            *(ushort8*)(Cb + (size_t)(row0 + hh * 64 + rrow) * 4096 + col0 + off) =
                *(const ushort8*)&ep[rrow * 128 + off];
        }
        __syncthreads();
    }
}

// ---------------------------------------------------------------------------
// GEMM6 dedicated: out = y @ out_proj_w^T, 128x64 tile (grid 16x32 = 512
// blocks = 2 blocks/CU), K=2048, direct fp32 stores. No split, no reduce.
// ---------------------------------------------------------------------------
__global__ __launch_bounds__(256) void gemm_out64(
    const unsigned short* __restrict__ A,   // yb [4096][2048]
    const unsigned short* __restrict__ B,   // outw [1024][2048]
    float* __restrict__ out)                // [4096][1024]
{
    __shared__ unsigned short As[8][128 * 8];   // 16 KB
    __shared__ unsigned short Bs[8][64 * 8];    //  8 KB

    const int tid  = threadIdx.x;
    const int lane = tid & 63;
    const int w    = tid >> 6;
    const int wr   = w >> 1;          // 0..1: 64-row half
    const int wc   = w & 1;           // 0..1: 32-col half
    const int q    = lane >> 4;
    const int m    = lane & 15;
    const int row0 = blockIdx.y * 128;
    const int col0 = blockIdx.x * 64;

    f32x4 acc[4][2];
#pragma unroll
    for (int i = 0; i < 4; i++)
#pragma unroll
        for (int j = 0; j < 2; j++) acc[i][j] = (f32x4){0.f, 0.f, 0.f, 0.f};

    for (int k0 = 0; k0 < 2048; k0 += 64) {
        // A: 16 chunks of 1 KB (4 per wave); B: 8 chunks of 1 KB (2 per wave)
#pragma unroll
        for (int i = 0; i < 4; i++) {
            const int c    = w * 4 + i;
            const int kb   = c >> 1;
            const int half = c & 1;
            const unsigned short* ga =
                A + (size_t)(row0 + half * 64 + lane) * 2048 + k0 + kb * 8;
            __builtin_amdgcn_global_load_lds(
                (const __attribute__((address_space(1))) unsigned int*)ga,
                (__attribute__((address_space(3))) unsigned int*)&As[kb][half * 512],
                16, 0, 0);
        }
#pragma unroll
        for (int i = 0; i < 2; i++) {
            const int c = w * 2 + i;              // kb 0..7
            const unsigned short* gb =
                B + (size_t)(col0 + lane) * 2048 + k0 + c * 8;
            __builtin_amdgcn_global_load_lds(
                (const __attribute__((address_space(1))) unsigned int*)gb,
                (__attribute__((address_space(3))) unsigned int*)&Bs[c][0],
                16, 0, 0);
        }
        __syncthreads();

#pragma unroll
        for (int dep = 0; dep < 2; dep++) {
            bf16x8 af[4], bfr[2];
#pragma unroll
            for (int t = 0; t < 4; t++)
                af[t] = *(const bf16x8*)&As[dep * 4 + q][(wr * 64 + t * 16 + m) * 8];
#pragma unroll
            for (int t = 0; t < 2; t++)
                bfr[t] = *(const bf16x8*)&Bs[dep * 4 + q][(wc * 32 + t * 16 + m) * 8];
#pragma unroll
            for (int mt = 0; mt < 4; mt++)
#pragma unroll
                for (int nt = 0; nt < 2; nt++)
                    acc[mt][nt] = __builtin_amdgcn_mfma_f32_16x16x32_bf16(
                        af[mt], bfr[nt], acc[mt][nt], 0, 0, 0);
        }
        __syncthreads();
    }

#pragma unroll
    for (int mt = 0; mt < 4; mt++) {
#pragma unroll
        for (int nt = 0; nt < 2; nt++) {
            const int col = col0 + wc * 32 + nt * 16 + m;
#pragma unroll
            for (int r = 0; r < 4; r++) {
                const int row = row0 + wr * 64 + mt * 16 + q * 4 + r;
                out[(size_t)row * D_MODEL + col] = acc[mt][nt][r];
            }
        }
    }
}

// ---------------------------------------------------------------------------
// GEMM4 dedicated: dt = softplus(dt_r @ dt_proj_w^T + b) -> fp16.
// ---------------------------------------------------------------------------
__global__ __launch_bounds__(256) void gemm_dt16(
    const unsigned short* __restrict__ A,
    const unsigned short* __restrict__ B,
    unsigned short* __restrict__ Cb,        // [4096][2048] fp16
    const float* __restrict__ bias)
{
    __shared__ unsigned short As[8][128 * 8];
    __shared__ unsigned short Bs[8][128 * 8];

    const int tid  = threadIdx.x;
    const int lane = tid & 63;
    const int w    = tid >> 6;
    const int wr   = w >> 1;
    const int wc   = w & 1;
    const int q    = lane >> 4;
    const int m    = lane & 15;
    const int row0 = blockIdx.y * 128;
    const int col0 = blockIdx.x * 128;

    f32x4 acc[4][4];
#pragma unroll
    for (int i = 0; i < 4; i++)
#pragma unroll
        for (int j = 0; j < 4; j++) acc[i][j] = (f32x4){0.f, 0.f, 0.f, 0.f};

    {
#pragma unroll
        for (int i = 0; i < 4; i++) {
            const int c    = w * 4 + i;
            const int kb   = c >> 1;
            const int half = c & 1;
            const unsigned short* ga =
                A + (size_t)(row0 + half * 64 + lane) * 96 + kb * 8;
            const unsigned short* gb =
                B + (size_t)(col0 + half * 64 + lane) * 64 + kb * 8;
            __builtin_amdgcn_global_load_lds(
                (const __attribute__((address_space(1))) unsigned int*)ga,
                (__attribute__((address_space(3))) unsigned int*)&As[kb][half * 512],
                16, 0, 0);
            __builtin_amdgcn_global_load_lds(
                (const __attribute__((address_space(1))) unsigned int*)gb,
                (__attribute__((address_space(3))) unsigned int*)&Bs[kb][half * 512],
                16, 0, 0);
        }
        __syncthreads();

#pragma unroll
        for (int dep = 0; dep < 2; dep++) {
            bf16x8 af[4], bfr[4];
#pragma unroll
            for (int t = 0; t < 4; t++) {
                af[t]  = *(const bf16x8*)&As[dep * 4 + q][(wr * 64 + t * 16 + m) * 8];
                bfr[t] = *(const bf16x8*)&Bs[dep * 4 + q][(wc * 64 + t * 16 + m) * 8];
            }
#pragma unroll
            for (int mt = 0; mt < 4; mt++)
#pragma unroll
                for (int nt = 0; nt < 4; nt++)
                    acc[mt][nt] = __builtin_amdgcn_mfma_f32_16x16x32_bf16(
                        af[mt], bfr[nt], acc[mt][nt], 0, 0, 0);
        }
        __syncthreads();
    }

    unsigned short* ep = &As[0][0];
#pragma unroll
    for (int hh = 0; hh < 2; hh++) {
        if (wr == hh) {
#pragma unroll
            for (int mt = 0; mt < 4; mt++)
#pragma unroll
                for (int nt = 0; nt < 4; nt++) {
                    const int col = col0 + wc * 64 + nt * 16 + m;
                    const float bcol = bias[col];
#pragma unroll
                    for (int r = 0; r < 4; r++)
                        ep[(mt * 16 + q * 4 + r) * 128 + wc * 64 + nt * 16 + m] =
                            f2h(softplus_f(acc[mt][nt][r] + bcol));
                }
        }
        __syncthreads();
#pragma unroll
        for (int i = 0; i < 4; i++) {
            const int c    = i * 256 + tid;
            const int rrow = c >> 4;
            const int off  = (c & 15) * 8;
            *(ushort8*)(Cb + (size_t)(row0 + hh * 64 + rrow) * D_INNER + col0 + off) =
                *(const ushort8*)&ep[rrow * 128 + off];
        }
        __syncthreads();
    }
}

// ---------------------------------------------------------------------------
// GEMM3 bf16 split-K: x_dbl = xc_bf[4096,2048] @ xpw_pad[128,2048]^T.
// ---------------------------------------------------------------------------
#define G3Z 8

__global__ __launch_bounds__(256) void gemm3_bf16_splitk(
    const unsigned short* __restrict__ A,   // [4096][2048]
    const unsigned short* __restrict__ B,   // [128][2048] padded
    float* __restrict__ Cp)                 // [G3Z][4096][96]
{
    __shared__ unsigned short As[8][128 * 8];
    __shared__ unsigned short Bs[8][128 * 8];

    const int tid  = threadIdx.x;
    const int lane = tid & 63;
    const int w    = tid >> 6;
    const int wr   = w >> 1;
    const int wc   = w & 1;
    const int q    = lane >> 4;
    const int m    = lane & 15;
    const int row0 = blockIdx.y * 128;
    const int kz0  = blockIdx.z * (2048 / G3Z);

    f32x4 acc[4][4];
#pragma unroll
    for (int i = 0; i < 4; i++)
#pragma unroll
        for (int j = 0; j < 4; j++) acc[i][j] = (f32x4){0.f, 0.f, 0.f, 0.f};

    for (int k0 = kz0; k0 < kz0 + (2048 / G3Z); k0 += 64) {
#pragma unroll
        for (int i = 0; i < 4; i++) {
            const int c    = w * 4 + i;
            const int kb   = c >> 1;
            const int half = c & 1;
            const unsigned short* ga =
                A + (size_t)(row0 + half * 64 + lane) * 2048 + k0 + kb * 8;
            const unsigned short* gb =
                B + (size_t)(half * 64 + lane) * 2048 + k0 + kb * 8;
            __builtin_amdgcn_global_load_lds(
                (const __attribute__((address_space(1))) unsigned int*)ga,
                (__attribute__((address_space(3))) unsigned int*)&As[kb][half * 512],
                16, 0, 0);
            __builtin_amdgcn_global_load_lds(
                (const __attribute__((address_space(1))) unsigned int*)gb,
                (__attribute__((address_space(3))) unsigned int*)&Bs[kb][half * 512],
                16, 0, 0);
        }
        __syncthreads();

#pragma unroll
        for (int dep = 0; dep < 2; dep++) {
            bf16x8 af[4], bfr[4];
#pragma unroll
            for (int t = 0; t < 4; t++) {
                af[t]  = *(const bf16x8*)&As[dep * 4 + q][(wr * 64 + t * 16 + m) * 8];
                bfr[t] = *(const bf16x8*)&Bs[dep * 4 + q][(wc * 64 + t * 16 + m) * 8];
            }
#pragma unroll
            for (int mt = 0; mt < 4; mt++)
#pragma unroll
                for (int nt = 0; nt < 4; nt++)
                    acc[mt][nt] = __builtin_amdgcn_mfma_f32_16x16x32_bf16(
                        af[mt], bfr[nt], acc[mt][nt], 0, 0, 0);
        }
        __syncthreads();
    }

    float* Cz = Cp + (size_t)blockIdx.z * NROW * 96;
#pragma unroll
    for (int mt = 0; mt < 4; mt++) {
#pragma unroll
        for (int nt = 0; nt < 4; nt++) {
            const int col = wc * 64 + nt * 16 + m;
            if (col < 96) {
#pragma unroll
                for (int r = 0; r < 4; r++) {
                    const int row = row0 + wr * 64 + mt * 16 + q * 4 + r;
                    Cz[(size_t)row * 96 + col] = acc[mt][nt][r];
                }
            }
        }
    }
}

__global__ __launch_bounds__(256) void reduce3(
    const float* __restrict__ Cp,
    float* __restrict__ xdbl,
    unsigned short* __restrict__ xdbl_bf)
{
    const int idx = blockIdx.x * 256 + threadIdx.x;   // < 4096*96
    float s = 0.f;
#pragma unroll
    for (int z = 0; z < G3Z; z++)
        s += Cp[(size_t)z * NROW * 96 + idx];
    xdbl[idx] = s;
    xdbl_bf[idx] = f2bf(s);
}

// ---------------------------------------------------------------------------
// Causal depthwise conv1d (K=4, left-pad 3) + bias + SiLU, 8 channels/thread.
// ---------------------------------------------------------------------------
__global__ __launch_bounds__(256) void conv_silu8(
    const unsigned short* __restrict__ xz,   // [NROW][2*D_INNER] bf16
    const float* __restrict__ conv_w,        // [D_INNER][4]
    const float* __restrict__ conv_b,
    unsigned short* __restrict__ xc_bf)      // [NROW][D_INNER] bf16
{
    const int i8 = (blockIdx.x * 256 + threadIdx.x) * 8;  // over NROW*D_INNER
    const int d0 = i8 & (D_INNER - 1);
    const int rt = i8 >> 11;
    const int t  = rt & (L_SEQ - 1);

    const unsigned short* base = xz + (size_t)rt * (2 * D_INNER) + d0;
    ushort8 v0, v1, v2, v3;
    v3 = *(const ushort8*)(base);
    v2 = (t >= 1) ? *(const ushort8*)(base - 1 * 2 * D_INNER) : (ushort8)0;
    v1 = (t >= 2) ? *(const ushort8*)(base - 2 * 2 * D_INNER) : (ushort8)0;
    v0 = (t >= 3) ? *(const ushort8*)(base - 3 * 2 * D_INNER) : (ushort8)0;

    ushort8 o;
#pragma unroll
    for (int j = 0; j < 8; j++) {
        const float4 wv = *(const float4*)(conv_w + (d0 + j) * 4);
        float acc = conv_b[d0 + j];
        acc = fmaf(wv.x, bf2f(v0[j]), acc);
        acc = fmaf(wv.y, bf2f(v1[j]), acc);
        acc = fmaf(wv.z, bf2f(v2[j]), acc);
        acc = fmaf(wv.w, bf2f(v3[j]), acc);
        const float sig = 1.f / (1.f + __expf(-acc));
        o[j] = f2bf(acc * sig);
    }
    *(ushort8*)(xc_bf + i8) = o;
}

// ---------------------------------------------------------------------------
// Chunked parallel selective scan, thread-per-d with h[16] in registers.
// ---------------------------------------------------------------------------
#define G_CHUNK 32
#define T_CHUNK (L_SEQ / G_CHUNK)   // 64

__global__ __launch_bounds__(256) void scan_pass1(
    const unsigned short* __restrict__ dth,     // [NROW][D_INNER] fp16
    const unsigned short* __restrict__ xc,      // [NROW][D_INNER] bf16
    const float* __restrict__ xdbl,             // [NROW][96]
    const float* __restrict__ A_log,            // [D_INNER][16]
    float* __restrict__ aprod,                  // [G][B][16][D_INNER]
    float* __restrict__ hend)
{
    __shared__ float B_s[T_CHUNK][16];

    const int tid = threadIdx.x;
    const int g   = blockIdx.x;
    const int db  = blockIdx.y;
    const int b   = db >> 3;
    const int d   = (db & 7) * 256 + tid;
    const size_t rowbase = (size_t)b * L_SEQ + (size_t)g * T_CHUNK;

    {
        const int tt = tid >> 2, q4 = (tid & 3) * 4;
        *(float4*)&B_s[tt][q4] =
            *(const float4*)&xdbl[(rowbase + tt) * 96 + DT_RANK + q4];
    }

    float A_dn[16];
#pragma unroll
    for (int n = 0; n < 16; n++)
        A_dn[n] = -expf(A_log[(size_t)d * D_STATE + n]);

    float h[16], ap[16];
#pragma unroll
    for (int n = 0; n < 16; n++) { h[n] = 0.f; ap[n] = 1.f; }

    __syncthreads();

#pragma unroll 2
    for (int t = 0; t < T_CHUNK; t++) {
        const size_t r = rowbase + t;
        const float dtv = h2f(dth[r * D_INNER + d]);
        const float xv  = bf2f(xc[r * D_INNER + d]);
        const float dtx = dtv * xv;
        float Bv[16];
        *(float4*)&Bv[0]  = *(const float4*)&B_s[t][0];
        *(float4*)&Bv[4]  = *(const float4*)&B_s[t][4];
        *(float4*)&Bv[8]  = *(const float4*)&B_s[t][8];
        *(float4*)&Bv[12] = *(const float4*)&B_s[t][12];
#pragma unroll
        for (int n = 0; n < 16; n++) {
            const float dA = __expf(dtv * A_dn[n]);
            ap[n] *= dA;
            h[n] = fmaf(dA, h[n], dtx * Bv[n]);
        }
    }

    const size_t base = ((size_t)g * B_SZ + b) * D_STATE * D_INNER + d;
#pragma unroll
    for (int n = 0; n < 16; n++) {
        aprod[base + (size_t)n * D_INNER] = ap[n];
        hend[base + (size_t)n * D_INNER]  = h[n];
    }
}

__global__ __launch_bounds__(256) void scan_pass2(
    const float* __restrict__ aprod,
    const float* __restrict__ hend,
    float* __restrict__ H0)
{
    const int idx = blockIdx.x * 256 + threadIdx.x;
    const size_t stride = (size_t)B_SZ * D_STATE * D_INNER;
    float h = 0.f;
#pragma unroll
    for (int g = 0; g < G_CHUNK; g++) {
        H0[(size_t)g * stride + idx] = h;
        h = fmaf(aprod[(size_t)g * stride + idx], h, hend[(size_t)g * stride + idx]);
    }
}

__global__ __launch_bounds__(256) void scan_pass3(
    const unsigned short* __restrict__ dth,    // fp16
    const unsigned short* __restrict__ xc,     // bf16
    const unsigned short* __restrict__ xz,     // bf16, z at +D_INNER
    const float* __restrict__ xdbl,
    const float* __restrict__ A_log,
    const float* __restrict__ Dvec,
    const float* __restrict__ H0,
    unsigned short* __restrict__ y)            // bf16
{
    __shared__ float B_s[T_CHUNK][16];
    __shared__ float C_s[T_CHUNK][16];

    const int tid = threadIdx.x;
    const int g   = blockIdx.x;
    const int db  = blockIdx.y;
    const int b   = db >> 3;
    const int d   = (db & 7) * 256 + tid;
    const size_t rowbase = (size_t)b * L_SEQ + (size_t)g * T_CHUNK;

    {
        const int tt = tid >> 2, q4 = (tid & 3) * 4;
        *(float4*)&B_s[tt][q4] =
            *(const float4*)&xdbl[(rowbase + tt) * 96 + DT_RANK + q4];
        *(float4*)&C_s[tt][q4] =
            *(const float4*)&xdbl[(rowbase + tt) * 96 + DT_RANK + D_STATE + q4];
    }

    float A_dn[16];
#pragma unroll
    for (int n = 0; n < 16; n++)
        A_dn[n] = -expf(A_log[(size_t)d * D_STATE + n]);
    const float D_d = Dvec[d];

    float h[16];
    const size_t base = ((size_t)g * B_SZ + b) * D_STATE * D_INNER + d;
#pragma unroll
    for (int n = 0; n < 16; n++)
        h[n] = H0[base + (size_t)n * D_INNER];

    __syncthreads();

#pragma unroll 2
    for (int t = 0; t < T_CHUNK; t++) {
        const size_t r = rowbase + t;
        const float dtv = h2f(dth[r * D_INNER + d]);
        const float xv  = bf2f(xc[r * D_INNER + d]);
        const float zv  = bf2f(xz[r * (2 * D_INNER) + D_INNER + d]);
        const float dtx = dtv * xv;
        float Bv[16], Cv[16];
        *(float4*)&Bv[0]  = *(const float4*)&B_s[t][0];
        *(float4*)&Bv[4]  = *(const float4*)&B_s[t][4];
        *(float4*)&Bv[8]  = *(const float4*)&B_s[t][8];
        *(float4*)&Bv[12] = *(const float4*)&B_s[t][12];
        *(float4*)&Cv[0]  = *(const float4*)&C_s[t][0];
        *(float4*)&Cv[4]  = *(const float4*)&C_s[t][4];
        *(float4*)&Cv[8]  = *(const float4*)&C_s[t][8];
        *(float4*)&Cv[12] = *(const float4*)&C_s[t][12];
        float dot = 0.f;
#pragma unroll
        for (int n = 0; n < 16; n++) {
            const float dA = __expf(dtv * A_dn[n]);
            h[n] = fmaf(dA, h[n], dtx * Bv[n]);
            dot = fmaf(h[n], Cv[n], dot);
        }
        const float sig = 1.f / (1.f + __expf(-zv));
        const float yv = (dot + D_d * xv) * (zv * sig);
        y[r * D_INNER + d] = f2bf(yv);
    }
}

// ---------------------------------------------------------------------------
extern "C" void kernel_launch(void* const* d_in, const int* in_sizes, int n_in,
                              void* d_out, int out_size, void* d_ws, size_t ws_size,
                              hipStream_t stream) {
    const float* x          = (const float*)d_in[0];
    const float* in_proj_w  = (const float*)d_in[1];
    const float* conv_w     = (const float*)d_in[2];
    const float* conv_b     = (const float*)d_in[3];
    const float* x_proj_w   = (const float*)d_in[4];
    const float* dt_proj_w  = (const float*)d_in[5];
    const float* dt_proj_b  = (const float*)d_in[6];
    const float* A_log      = (const float*)d_in[7];
    const float* Dv         = (const float*)d_in[8];
    const float* out_proj_w = (const float*)d_in[9];
    float* out = (float*)d_out;

    float* ws = (float*)d_ws;
    float* xdbl = ws;                                   //   393,216 f
    float* apr  = xdbl + (size_t)393216;                // 2,097,152 f
    float* hen  = apr  + (size_t)2097152;               // 2,097,152 f
    float* H0   = hen  + (size_t)2097152;               // 2,097,152 f
    float* Cp3  = H0   + (size_t)2097152;               // 3,145,728 f
    float* Cp6  = Cp3  + (size_t)3145728;               // 8,388,608 f (unused; layout kept)
    unsigned short* xz_bf   = (unsigned short*)(Cp6 + 8388608);  // 16,777,216 us
    unsigned short* xc_bf   = xz_bf   + (size_t)16777216;        //  8,388,608 us
    unsigned short* yb_bf   = xc_bf   + (size_t)8388608;         //  8,388,608 us
    unsigned short* dth     = yb_bf   + (size_t)8388608;         //  8,388,608 us (fp16)
    unsigned short* x_bf    = dth     + (size_t)8388608;         //  4,194,304 us
    unsigned short* inw_bf  = x_bf    + (size_t)4194304;         //  4,194,304 us
    unsigned short* dtw_bf  = inw_bf  + (size_t)4194304;         //    131,072 us
    unsigned short* outw_bf = dtw_bf  + (size_t)131072;          //  2,097,152 us
    unsigned short* xpw_bf  = outw_bf + (size_t)2097152;         //    262,144 us
    unsigned short* xdbl_bf = xpw_bf  + (size_t)262144;          //    393,216 us

    dim3 blk(256);

    // 0) all fp32->bf16 conversions (single launch)
    cvt_all<<<dim3(S_ALL / 1024), blk, 0, stream>>>(
        x, in_proj_w, dt_proj_w, out_proj_w, x_proj_w,
        x_bf, inw_bf, dtw_bf, outw_bf, xpw_bf);

    // 1) xz = x @ in_proj_w^T   (M=4096, N=4096, K=1024) -> bf16, XCD swizzle
    gemm_in<<<dim3(1024), blk, 0, stream>>>(x_bf, inw_bf, xz_bf);

    // 2) conv + bias + SiLU -> xc_bf (8 channels/thread)
    conv_silu8<<<dim3((NROW * D_INNER) / (256 * 8)), blk, 0, stream>>>(
        xz_bf, conv_w, conv_b, xc_bf);

    // 3) x_dbl = xc @ x_proj_w^T (split-K bf16)
    gemm3_bf16_splitk<<<dim3(1, 32, G3Z), blk, 0, stream>>>(xc_bf, xpw_bf, Cp3);
    reduce3<<<dim3((NROW * 96) / 256), blk, 0, stream>>>(Cp3, xdbl, xdbl_bf);

    // 4) dt = softplus(dt_r @ dt_proj_w^T + b) -> fp16
    gemm_dt16<<<dim3(16, 32), blk, 0, stream>>>(
        xdbl_bf, dtw_bf, dth, dt_proj_b);

    // 5) chunked parallel selective scan -> yb (bf16)
    scan_pass1<<<dim3(G_CHUNK, 16), blk, 0, stream>>>(
        dth, xc_bf, xdbl, A_log, apr, hen);
    scan_pass2<<<dim3(B_SZ * D_STATE * D_INNER / 256), blk, 0, stream>>>(
        apr, hen, H0);
    scan_pass3<<<dim3(G_CHUNK, 16), blk, 0, stream>>>(
        dth, xc_bf, xz_bf, xdbl, A_log, Dv, H0, yb_bf);

    // 6) out = y @ out_proj_w^T, 128x64 tile, 512 blocks, direct fp32 store
    gemm_out64<<<dim3(16, 32), blk, 0, stream>>>(yb_bf, outw_bf, out);
}

// Round 10
// 380.733 us; speedup vs baseline: 1.5582x; 1.5582x over previous
//
#include <hip/hip_runtime.h>
#include <math.h>

#define D_MODEL 1024
#define D_STATE 16
#define D_CONV  4
#define D_INNER 2048
#define DT_RANK 64
#define B_SZ    2
#define L_SEQ   2048
#define NROW    (B_SZ * L_SEQ)   // 4096

typedef __bf16 bf16x8 __attribute__((ext_vector_type(8)));
typedef float  f32x4  __attribute__((ext_vector_type(4)));
typedef unsigned short ushort8 __attribute__((ext_vector_type(8)));

__device__ __forceinline__ unsigned short f2bf(float f) {
    unsigned u = __float_as_uint(f);
    u += 0x7fff + ((u >> 16) & 1);       // RNE
    return (unsigned short)(u >> 16);
}
__device__ __forceinline__ float bf2f(unsigned short v) {
    return __uint_as_float((unsigned)v << 16);
}
__device__ __forceinline__ float softplus_f(float x) {
    return (x > 20.f) ? x : log1pf(__expf(x));
}

// ---------------------------------------------------------------------------
// Batched fp32 -> bf16 conversion: x, in_proj_w, dt_proj_w, out_proj_w,
// plus x_proj_w padded [96][2048] -> [128][2048].
// ---------------------------------------------------------------------------
#define S_X    (NROW * D_MODEL)                 // 4,194,304
#define S_IN   (2 * D_INNER * D_MODEL)          // 4,194,304
#define S_DT   (D_INNER * DT_RANK)              //   131,072
#define S_OUT  (D_MODEL * D_INNER)              // 2,097,152
#define S_TOT  (S_X + S_IN + S_DT + S_OUT)      // 10,616,832
#define S_PAD  (128 * 2048)                     //   262,144
#define S_ALL  (S_TOT + S_PAD)                  // 10,878,976

__global__ __launch_bounds__(256) void cvt_all(
    const float* __restrict__ x,   const float* __restrict__ inw,
    const float* __restrict__ dtw, const float* __restrict__ outw,
    const float* __restrict__ xpw,
    unsigned short* __restrict__ x_bf,   unsigned short* __restrict__ inw_bf,
    unsigned short* __restrict__ dtw_bf, unsigned short* __restrict__ outw_bf,
    unsigned short* __restrict__ xpw_bf)
{
    const int i = (blockIdx.x * 256 + threadIdx.x) * 4;
    if (i >= S_ALL) return;
    if (i >= S_TOT) {   // padded x_proj_w segment
        const int off = i - S_TOT;
        const int row = off >> 11;
        ushort4 o = make_ushort4(0, 0, 0, 0);
        if (row < 96) {
            const float4 v = *(const float4*)(xpw + (size_t)row * 2048 + (off & 2047));
            o.x = f2bf(v.x); o.y = f2bf(v.y); o.z = f2bf(v.z); o.w = f2bf(v.w);
        }
        *(ushort4*)(xpw_bf + off) = o;
        return;
    }
    const float* src; unsigned short* dst; int off;
    if (i < S_X)                    { src = x;    dst = x_bf;    off = i; }
    else if (i < S_X + S_IN)        { src = inw;  dst = inw_bf;  off = i - S_X; }
    else if (i < S_X + S_IN + S_DT) { src = dtw;  dst = dtw_bf;  off = i - S_X - S_IN; }
    else                            { src = outw; dst = outw_bf; off = i - S_X - S_IN - S_DT; }
    const float4 v = *(const float4*)(src + off);
    ushort4 o;
    o.x = f2bf(v.x); o.y = f2bf(v.y); o.z = f2bf(v.z); o.w = f2bf(v.w);
    *(ushort4*)(dst + off) = o;
}

// ---------------------------------------------------------------------------
// GEMM1 dedicated (round-8 proven: 75.2 us): xz = x_bf @ inw_bf^T -> bf16.
// 128x128 tile, BK=64, plain 2-D block mapping, __launch_bounds__(256,4).
// ---------------------------------------------------------------------------
__global__ __launch_bounds__(256, 4) void gemm_in(
    const unsigned short* __restrict__ A,
    const unsigned short* __restrict__ B,
    unsigned short* __restrict__ Cb)
{
    __shared__ unsigned short As[8][128 * 8];   // 16 KB
    __shared__ unsigned short Bs[8][128 * 8];   // 16 KB

    const int tid  = threadIdx.x;
    const int lane = tid & 63;
    const int w    = tid >> 6;
    const int wr   = w >> 1;
    const int wc   = w & 1;
    const int q    = lane >> 4;
    const int m    = lane & 15;
    const int row0 = blockIdx.y * 128;
    const int col0 = blockIdx.x * 128;

    f32x4 acc[4][4];
#pragma unroll
    for (int i = 0; i < 4; i++)
#pragma unroll
        for (int j = 0; j < 4; j++) acc[i][j] = (f32x4){0.f, 0.f, 0.f, 0.f};

    for (int k0 = 0; k0 < 1024; k0 += 64) {
#pragma unroll
        for (int i = 0; i < 4; i++) {
            const int c    = w * 4 + i;
            const int kb   = c >> 1;
            const int half = c & 1;
            const unsigned short* ga =
                A + (size_t)(row0 + half * 64 + lane) * 1024 + k0 + kb * 8;
            const unsigned short* gb =
                B + (size_t)(col0 + half * 64 + lane) * 1024 + k0 + kb * 8;
            __builtin_amdgcn_global_load_lds(
                (const __attribute__((address_space(1))) unsigned int*)ga,
                (__attribute__((address_space(3))) unsigned int*)&As[kb][half * 512],
                16, 0, 0);
            __builtin_amdgcn_global_load_lds(
                (const __attribute__((address_space(1))) unsigned int*)gb,
                (__attribute__((address_space(3))) unsigned int*)&Bs[kb][half * 512],
                16, 0, 0);
        }
        __syncthreads();

#pragma unroll
        for (int dep = 0; dep < 2; dep++) {
            bf16x8 af[4], bfr[4];
#pragma unroll
            for (int t = 0; t < 4; t++) {
                af[t]  = *(const bf16x8*)&As[dep * 4 + q][(wr * 64 + t * 16 + m) * 8];
                bfr[t] = *(const bf16x8*)&Bs[dep * 4 + q][(wc * 64 + t * 16 + m) * 8];
            }
#pragma unroll
            for (int mt = 0; mt < 4; mt++)
#pragma unroll
                for (int nt = 0; nt < 4; nt++)
                    acc[mt][nt] = __builtin_amdgcn_mfma_f32_16x16x32_bf16(
                        af[mt], bfr[nt], acc[mt][nt], 0, 0, 0);
        }
        __syncthreads();
    }

    // bf16 epilogue through LDS: two 64-row halves, reuse As
    unsigned short* ep = &As[0][0];
#pragma unroll
    for (int hh = 0; hh < 2; hh++) {
        if (wr == hh) {
#pragma unroll
            for (int mt = 0; mt < 4; mt++)
#pragma unroll
                for (int nt = 0; nt < 4; nt++)
#pragma unroll
                    for (int r = 0; r < 4; r++)
                        ep[(mt * 16 + q * 4 + r) * 128 + wc * 64 + nt * 16 + m] =
                            f2bf(acc[mt][nt][r]);
        }
        __syncthreads();
#pragma unroll
        for (int i = 0; i < 4; i++) {
            const int c    = i * 256 + tid;       // 0..1023
            const int rrow = c >> 4;
            const int off  = (c & 15) * 8;
            *(ushort8*)(Cb + (size_t)(row0 + hh * 64 + rrow) * 4096 + col0 + off) =
                *(const ushort8*)&ep[rrow * 128 + off];
        }
        __syncthreads();
    }
}

// ---------------------------------------------------------------------------
// GEMM4 (round-5 proven config): dt = softplus(dt_r @ dt_proj_w^T + b) -> fp32.
// A = xdbl_bf [4096][96], B = dtw_bf [2048][64], K=64 (one staging iter).
// Plain fp32 dword stores (round-5 mode 1 behavior).
// ---------------------------------------------------------------------------
__global__ __launch_bounds__(256) void gemm_dt_f32(
    const unsigned short* __restrict__ A,
    const unsigned short* __restrict__ B,
    float* __restrict__ C,                  // [4096][2048] fp32
    const float* __restrict__ bias)
{
    __shared__ unsigned short As[8][128 * 8];
    __shared__ unsigned short Bs[8][128 * 8];

    const int tid  = threadIdx.x;
    const int lane = tid & 63;
    const int w    = tid >> 6;
    const int wr   = w >> 1;
    const int wc   = w & 1;
    const int q    = lane >> 4;
    const int m    = lane & 15;
    const int row0 = blockIdx.y * 128;
    const int col0 = blockIdx.x * 128;

    f32x4 acc[4][4];
#pragma unroll
    for (int i = 0; i < 4; i++)
#pragma unroll
        for (int j = 0; j < 4; j++) acc[i][j] = (f32x4){0.f, 0.f, 0.f, 0.f};

    {
#pragma unroll
        for (int i = 0; i < 4; i++) {
            const int c    = w * 4 + i;
            const int kb   = c >> 1;
            const int half = c & 1;
            const unsigned short* ga =
                A + (size_t)(row0 + half * 64 + lane) * 96 + kb * 8;
            const unsigned short* gb =
                B + (size_t)(col0 + half * 64 + lane) * 64 + kb * 8;
            __builtin_amdgcn_global_load_lds(
                (const __attribute__((address_space(1))) unsigned int*)ga,
                (__attribute__((address_space(3))) unsigned int*)&As[kb][half * 512],
                16, 0, 0);
            __builtin_amdgcn_global_load_lds(
                (const __attribute__((address_space(1))) unsigned int*)gb,
                (__attribute__((address_space(3))) unsigned int*)&Bs[kb][half * 512],
                16, 0, 0);
        }
        __syncthreads();

#pragma unroll
        for (int dep = 0; dep < 2; dep++) {
            bf16x8 af[4], bfr[4];
#pragma unroll
            for (int t = 0; t < 4; t++) {
                af[t]  = *(const bf16x8*)&As[dep * 4 + q][(wr * 64 + t * 16 + m) * 8];
                bfr[t] = *(const bf16x8*)&Bs[dep * 4 + q][(wc * 64 + t * 16 + m) * 8];
            }
#pragma unroll
            for (int mt = 0; mt < 4; mt++)
#pragma unroll
                for (int nt = 0; nt < 4; nt++)
                    acc[mt][nt] = __builtin_amdgcn_mfma_f32_16x16x32_bf16(
                        af[mt], bfr[nt], acc[mt][nt], 0, 0, 0);
        }
        __syncthreads();
    }

#pragma unroll
    for (int mt = 0; mt < 4; mt++) {
#pragma unroll
        for (int nt = 0; nt < 4; nt++) {
            const int col = col0 + wc * 64 + nt * 16 + m;
            const float bcol = bias[col];
#pragma unroll
            for (int r = 0; r < 4; r++) {
                const int row = row0 + wr * 64 + mt * 16 + q * 4 + r;
                C[(size_t)row * D_INNER + col] = softplus_f(acc[mt][nt][r] + bcol);
            }
        }
    }
}

// ---------------------------------------------------------------------------
// GEMM6 dedicated: out = y @ out_proj_w^T, 128x64 tile (512 blocks = 2/CU),
// K=2048, direct fp32 stores. No split, no reduce, no atomics.
// ---------------------------------------------------------------------------
__global__ __launch_bounds__(256) void gemm_out64(
    const unsigned short* __restrict__ A,   // yb [4096][2048]
    const unsigned short* __restrict__ B,   // outw [1024][2048]
    float* __restrict__ out)                // [4096][1024]
{
    __shared__ unsigned short As[8][128 * 8];   // 16 KB
    __shared__ unsigned short Bs[8][64 * 8];    //  8 KB

    const int tid  = threadIdx.x;
    const int lane = tid & 63;
    const int w    = tid >> 6;
    const int wr   = w >> 1;          // 0..1: 64-row half
    const int wc   = w & 1;           // 0..1: 32-col half
    const int q    = lane >> 4;
    const int m    = lane & 15;
    const int row0 = blockIdx.y * 128;
    const int col0 = blockIdx.x * 64;

    f32x4 acc[4][2];
#pragma unroll
    for (int i = 0; i < 4; i++)
#pragma unroll
        for (int j = 0; j < 2; j++) acc[i][j] = (f32x4){0.f, 0.f, 0.f, 0.f};

    for (int k0 = 0; k0 < 2048; k0 += 64) {
#pragma unroll
        for (int i = 0; i < 4; i++) {
            const int c    = w * 4 + i;
            const int kb   = c >> 1;
            const int half = c & 1;
            const unsigned short* ga =
                A + (size_t)(row0 + half * 64 + lane) * 2048 + k0 + kb * 8;
            __builtin_amdgcn_global_load_lds(
                (const __attribute__((address_space(1))) unsigned int*)ga,
                (__attribute__((address_space(3))) unsigned int*)&As[kb][half * 512],
                16, 0, 0);
        }
#pragma unroll
        for (int i = 0; i < 2; i++) {
            const int c = w * 2 + i;              // kb 0..7
            const unsigned short* gb =
                B + (size_t)(col0 + lane) * 2048 + k0 + c * 8;
            __builtin_amdgcn_global_load_lds(
                (const __attribute__((address_space(1))) unsigned int*)gb,
                (__attribute__((address_space(3))) unsigned int*)&Bs[c][0],
                16, 0, 0);
        }
        __syncthreads();

#pragma unroll
        for (int dep = 0; dep < 2; dep++) {
            bf16x8 af[4], bfr[2];
#pragma unroll
            for (int t = 0; t < 4; t++)
                af[t] = *(const bf16x8*)&As[dep * 4 + q][(wr * 64 + t * 16 + m) * 8];
#pragma unroll
            for (int t = 0; t < 2; t++)
                bfr[t] = *(const bf16x8*)&Bs[dep * 4 + q][(wc * 32 + t * 16 + m) * 8];
#pragma unroll
            for (int mt = 0; mt < 4; mt++)
#pragma unroll
                for (int nt = 0; nt < 2; nt++)
                    acc[mt][nt] = __builtin_amdgcn_mfma_f32_16x16x32_bf16(
                        af[mt], bfr[nt], acc[mt][nt], 0, 0, 0);
        }
        __syncthreads();
    }

#pragma unroll
    for (int mt = 0; mt < 4; mt++) {
#pragma unroll
        for (int nt = 0; nt < 2; nt++) {
            const int col = col0 + wc * 32 + nt * 16 + m;
#pragma unroll
            for (int r = 0; r < 4; r++) {
                const int row = row0 + wr * 64 + mt * 16 + q * 4 + r;
                out[(size_t)row * D_MODEL + col] = acc[mt][nt][r];
            }
        }
    }
}

// ---------------------------------------------------------------------------
// GEMM3 bf16 split-K: x_dbl = xc_bf[4096,2048] @ xpw_pad[128,2048]^T.
// ---------------------------------------------------------------------------
#define G3Z 8

__global__ __launch_bounds__(256) void gemm3_bf16_splitk(
    const unsigned short* __restrict__ A,   // [4096][2048]
    const unsigned short* __restrict__ B,   // [128][2048] padded
    float* __restrict__ Cp)                 // [G3Z][4096][96]
{
    __shared__ unsigned short As[8][128 * 8];
    __shared__ unsigned short Bs[8][128 * 8];

    const int tid  = threadIdx.x;
    const int lane = tid & 63;
    const int w    = tid >> 6;
    const int wr   = w >> 1;
    const int wc   = w & 1;
    const int q    = lane >> 4;
    const int m    = lane & 15;
    const int row0 = blockIdx.y * 128;
    const int kz0  = blockIdx.z * (2048 / G3Z);

    f32x4 acc[4][4];
#pragma unroll
    for (int i = 0; i < 4; i++)
#pragma unroll
        for (int j = 0; j < 4; j++) acc[i][j] = (f32x4){0.f, 0.f, 0.f, 0.f};

    for (int k0 = kz0; k0 < kz0 + (2048 / G3Z); k0 += 64) {
#pragma unroll
        for (int i = 0; i < 4; i++) {
            const int c    = w * 4 + i;
            const int kb   = c >> 1;
            const int half = c & 1;
            const unsigned short* ga =
                A + (size_t)(row0 + half * 64 + lane) * 2048 + k0 + kb * 8;
            const unsigned short* gb =
                B + (size_t)(half * 64 + lane) * 2048 + k0 + kb * 8;
            __builtin_amdgcn_global_load_lds(
                (const __attribute__((address_space(1))) unsigned int*)ga,
                (__attribute__((address_space(3))) unsigned int*)&As[kb][half * 512],
                16, 0, 0);
            __builtin_amdgcn_global_load_lds(
                (const __attribute__((address_space(1))) unsigned int*)gb,
                (__attribute__((address_space(3))) unsigned int*)&Bs[kb][half * 512],
                16, 0, 0);
        }
        __syncthreads();

#pragma unroll
        for (int dep = 0; dep < 2; dep++) {
            bf16x8 af[4], bfr[4];
#pragma unroll
            for (int t = 0; t < 4; t++) {
                af[t]  = *(const bf16x8*)&As[dep * 4 + q][(wr * 64 + t * 16 + m) * 8];
                bfr[t] = *(const bf16x8*)&Bs[dep * 4 + q][(wc * 64 + t * 16 + m) * 8];
            }
#pragma unroll
            for (int mt = 0; mt < 4; mt++)
#pragma unroll
                for (int nt = 0; nt < 4; nt++)
                    acc[mt][nt] = __builtin_amdgcn_mfma_f32_16x16x32_bf16(
                        af[mt], bfr[nt], acc[mt][nt], 0, 0, 0);
        }
        __syncthreads();
    }

    float* Cz = Cp + (size_t)blockIdx.z * NROW * 96;
#pragma unroll
    for (int mt = 0; mt < 4; mt++) {
#pragma unroll
        for (int nt = 0; nt < 4; nt++) {
            const int col = wc * 64 + nt * 16 + m;
            if (col < 96) {
#pragma unroll
                for (int r = 0; r < 4; r++) {
                    const int row = row0 + wr * 64 + mt * 16 + q * 4 + r;
                    Cz[(size_t)row * 96 + col] = acc[mt][nt][r];
                }
            }
        }
    }
}

__global__ __launch_bounds__(256) void reduce3(
    const float* __restrict__ Cp,
    float* __restrict__ xdbl,
    unsigned short* __restrict__ xdbl_bf)
{
    const int idx = blockIdx.x * 256 + threadIdx.x;   // < 4096*96
    float s = 0.f;
#pragma unroll
    for (int z = 0; z < G3Z; z++)
        s += Cp[(size_t)z * NROW * 96 + idx];
    xdbl[idx] = s;
    xdbl_bf[idx] = f2bf(s);
}

// ---------------------------------------------------------------------------
// Causal depthwise conv1d (K=4, left-pad 3) + bias + SiLU, 8 channels/thread.
// ---------------------------------------------------------------------------
__global__ __launch_bounds__(256) void conv_silu8(
    const unsigned short* __restrict__ xz,   // [NROW][2*D_INNER] bf16
    const float* __restrict__ conv_w,        // [D_INNER][4]
    const float* __restrict__ conv_b,
    unsigned short* __restrict__ xc_bf)      // [NROW][D_INNER] bf16
{
    const int i8 = (blockIdx.x * 256 + threadIdx.x) * 8;  // over NROW*D_INNER
    const int d0 = i8 & (D_INNER - 1);
    const int rt = i8 >> 11;
    const int t  = rt & (L_SEQ - 1);

    const unsigned short* base = xz + (size_t)rt * (2 * D_INNER) + d0;
    ushort8 v0, v1, v2, v3;
    v3 = *(const ushort8*)(base);
    v2 = (t >= 1) ? *(const ushort8*)(base - 1 * 2 * D_INNER) : (ushort8)0;
    v1 = (t >= 2) ? *(const ushort8*)(base - 2 * 2 * D_INNER) : (ushort8)0;
    v0 = (t >= 3) ? *(const ushort8*)(base - 3 * 2 * D_INNER) : (ushort8)0;

    ushort8 o;
#pragma unroll
    for (int j = 0; j < 8; j++) {
        const float4 wv = *(const float4*)(conv_w + (d0 + j) * 4);
        float acc = conv_b[d0 + j];
        acc = fmaf(wv.x, bf2f(v0[j]), acc);
        acc = fmaf(wv.y, bf2f(v1[j]), acc);
        acc = fmaf(wv.z, bf2f(v2[j]), acc);
        acc = fmaf(wv.w, bf2f(v3[j]), acc);
        const float sig = 1.f / (1.f + __expf(-acc));
        o[j] = f2bf(acc * sig);
    }
    *(ushort8*)(xc_bf + i8) = o;
}

// ---------------------------------------------------------------------------
// Chunked parallel selective scan, thread-per-d with h[16] in registers.
// dt is fp32 (round-5 proven path).
// ---------------------------------------------------------------------------
#define G_CHUNK 32
#define T_CHUNK (L_SEQ / G_CHUNK)   // 64

__global__ __launch_bounds__(256) void scan_pass1(
    const float* __restrict__ dtbuf,            // [NROW][D_INNER] fp32
    const unsigned short* __restrict__ xc,      // [NROW][D_INNER] bf16
    const float* __restrict__ xdbl,             // [NROW][96]
    const float* __restrict__ A_log,            // [D_INNER][16]
    float* __restrict__ aprod,                  // [G][B][16][D_INNER]
    float* __restrict__ hend)
{
    __shared__ float B_s[T_CHUNK][16];

    const int tid = threadIdx.x;
    const int g   = blockIdx.x;
    const int db  = blockIdx.y;
    const int b   = db >> 3;
    const int d   = (db & 7) * 256 + tid;
    const size_t rowbase = (size_t)b * L_SEQ + (size_t)g * T_CHUNK;

    {
        const int tt = tid >> 2, q4 = (tid & 3) * 4;
        *(float4*)&B_s[tt][q4] =
            *(const float4*)&xdbl[(rowbase + tt) * 96 + DT_RANK + q4];
    }

    float A_dn[16];
#pragma unroll
    for (int n = 0; n < 16; n++)
        A_dn[n] = -expf(A_log[(size_t)d * D_STATE + n]);

    float h[16], ap[16];
#pragma unroll
    for (int n = 0; n < 16; n++) { h[n] = 0.f; ap[n] = 1.f; }

    __syncthreads();

#pragma unroll 2
    for (int t = 0; t < T_CHUNK; t++) {
        const size_t r = rowbase + t;
        const float dtv = dtbuf[r * D_INNER + d];
        const float xv  = bf2f(xc[r * D_INNER + d]);
        const float dtx = dtv * xv;
        float Bv[16];
        *(float4*)&Bv[0]  = *(const float4*)&B_s[t][0];
        *(float4*)&Bv[4]  = *(const float4*)&B_s[t][4];
        *(float4*)&Bv[8]  = *(const float4*)&B_s[t][8];
        *(float4*)&Bv[12] = *(const float4*)&B_s[t][12];
#pragma unroll
        for (int n = 0; n < 16; n++) {
            const float dA = __expf(dtv * A_dn[n]);
            ap[n] *= dA;
            h[n] = fmaf(dA, h[n], dtx * Bv[n]);
        }
    }

    const size_t base = ((size_t)g * B_SZ + b) * D_STATE * D_INNER + d;
#pragma unroll
    for (int n = 0; n < 16; n++) {
        aprod[base + (size_t)n * D_INNER] = ap[n];
        hend[base + (size_t)n * D_INNER]  = h[n];
    }
}

__global__ __launch_bounds__(256) void scan_pass2(
    const float* __restrict__ aprod,
    const float* __restrict__ hend,
    float* __restrict__ H0)
{
    const int idx = blockIdx.x * 256 + threadIdx.x;
    const size_t stride = (size_t)B_SZ * D_STATE * D_INNER;
    float h = 0.f;
#pragma unroll
    for (int g = 0; g < G_CHUNK; g++) {
        H0[(size_t)g * stride + idx] = h;
        h = fmaf(aprod[(size_t)g * stride + idx], h, hend[(size_t)g * stride + idx]);
    }
}

__global__ __launch_bounds__(256) void scan_pass3(
    const float* __restrict__ dtbuf,           // fp32
    const unsigned short* __restrict__ xc,     // bf16
    const unsigned short* __restrict__ xz,     // bf16, z at +D_INNER
    const float* __restrict__ xdbl,
    const float* __restrict__ A_log,
    const float* __restrict__ Dvec,
    const float* __restrict__ H0,
    unsigned short* __restrict__ y)            // bf16
{
    __shared__ float B_s[T_CHUNK][16];
    __shared__ float C_s[T_CHUNK][16];

    const int tid = threadIdx.x;
    const int g   = blockIdx.x;
    const int db  = blockIdx.y;
    const int b   = db >> 3;
    const int d   = (db & 7) * 256 + tid;
    const size_t rowbase = (size_t)b * L_SEQ + (size_t)g * T_CHUNK;

    {
        const int tt = tid >> 2, q4 = (tid & 3) * 4;
        *(float4*)&B_s[tt][q4] =
            *(const float4*)&xdbl[(rowbase + tt) * 96 + DT_RANK + q4];
        *(float4*)&C_s[tt][q4] =
            *(const float4*)&xdbl[(rowbase + tt) * 96 + DT_RANK + D_STATE + q4];
    }

    float A_dn[16];
#pragma unroll
    for (int n = 0; n < 16; n++)
        A_dn[n] = -expf(A_log[(size_t)d * D_STATE + n]);
    const float D_d = Dvec[d];

    float h[16];
    const size_t base = ((size_t)g * B_SZ + b) * D_STATE * D_INNER + d;
#pragma unroll
    for (int n = 0; n < 16; n++)
        h[n] = H0[base + (size_t)n * D_INNER];

    __syncthreads();

#pragma unroll 2
    for (int t = 0; t < T_CHUNK; t++) {
        const size_t r = rowbase + t;
        const float dtv = dtbuf[r * D_INNER + d];
        const float xv  = bf2f(xc[r * D_INNER + d]);
        const float zv  = bf2f(xz[r * (2 * D_INNER) + D_INNER + d]);
        const float dtx = dtv * xv;
        float Bv[16], Cv[16];
        *(float4*)&Bv[0]  = *(const float4*)&B_s[t][0];
        *(float4*)&Bv[4]  = *(const float4*)&B_s[t][4];
        *(float4*)&Bv[8]  = *(const float4*)&B_s[t][8];
        *(float4*)&Bv[12] = *(const float4*)&B_s[t][12];
        *(float4*)&Cv[0]  = *(const float4*)&C_s[t][0];
        *(float4*)&Cv[4]  = *(const float4*)&C_s[t][4];
        *(float4*)&Cv[8]  = *(const float4*)&C_s[t][8];
        *(float4*)&Cv[12] = *(const float4*)&C_s[t][12];
        float dot = 0.f;
#pragma unroll
        for (int n = 0; n < 16; n++) {
            const float dA = __expf(dtv * A_dn[n]);
            h[n] = fmaf(dA, h[n], dtx * Bv[n]);
            dot = fmaf(h[n], Cv[n], dot);
        }
        const float sig = 1.f / (1.f + __expf(-zv));
        const float yv = (dot + D_d * xv) * (zv * sig);
        y[r * D_INNER + d] = f2bf(yv);
    }
}

// ---------------------------------------------------------------------------
extern "C" void kernel_launch(void* const* d_in, const int* in_sizes, int n_in,
                              void* d_out, int out_size, void* d_ws, size_t ws_size,
                              hipStream_t stream) {
    const float* x          = (const float*)d_in[0];
    const float* in_proj_w  = (const float*)d_in[1];
    const float* conv_w     = (const float*)d_in[2];
    const float* conv_b     = (const float*)d_in[3];
    const float* x_proj_w   = (const float*)d_in[4];
    const float* dt_proj_w  = (const float*)d_in[5];
    const float* dt_proj_b  = (const float*)d_in[6];
    const float* A_log      = (const float*)d_in[7];
    const float* Dv         = (const float*)d_in[8];
    const float* out_proj_w = (const float*)d_in[9];
    float* out = (float*)d_out;

    float* ws = (float*)d_ws;
    float* xdbl = ws;                                   //   393,216 f
    float* apr  = xdbl + (size_t)393216;                // 2,097,152 f
    float* hen  = apr  + (size_t)2097152;               // 2,097,152 f
    float* H0   = hen  + (size_t)2097152;               // 2,097,152 f
    float* Cp3  = H0   + (size_t)2097152;               // 3,145,728 f
    float* dtb  = Cp3  + (size_t)3145728;               // 8,388,608 f (fp32 dt)
    unsigned short* xz_bf   = (unsigned short*)(dtb + 8388608);  // 16,777,216 us
    unsigned short* xc_bf   = xz_bf   + (size_t)16777216;        //  8,388,608 us
    unsigned short* yb_bf   = xc_bf   + (size_t)8388608;         //  8,388,608 us
    unsigned short* x_bf    = yb_bf   + (size_t)8388608;         //  4,194,304 us
    unsigned short* inw_bf  = x_bf    + (size_t)4194304;         //  4,194,304 us
    unsigned short* dtw_bf  = inw_bf  + (size_t)4194304;         //    131,072 us
    unsigned short* outw_bf = dtw_bf  + (size_t)131072;          //  2,097,152 us
    unsigned short* xpw_bf  = outw_bf + (size_t)2097152;         //    262,144 us
    unsigned short* xdbl_bf = xpw_bf  + (size_t)262144;          //    393,216 us

    dim3 blk(256);

    // 0) all fp32->bf16 conversions (single launch)
    cvt_all<<<dim3(S_ALL / 1024), blk, 0, stream>>>(
        x, in_proj_w, dt_proj_w, out_proj_w, x_proj_w,
        x_bf, inw_bf, dtw_bf, outw_bf, xpw_bf);

    // 1) xz = x @ in_proj_w^T   (M=4096, N=4096, K=1024) -> bf16
    gemm_in<<<dim3(32, 32), blk, 0, stream>>>(x_bf, inw_bf, xz_bf);

    // 2) conv + bias + SiLU -> xc_bf (8 channels/thread)
    conv_silu8<<<dim3((NROW * D_INNER) / (256 * 8)), blk, 0, stream>>>(
        xz_bf, conv_w, conv_b, xc_bf);

    // 3) x_dbl = xc @ x_proj_w^T (split-K bf16)
    gemm3_bf16_splitk<<<dim3(1, 32, G3Z), blk, 0, stream>>>(xc_bf, xpw_bf, Cp3);
    reduce3<<<dim3((NROW * 96) / 256), blk, 0, stream>>>(Cp3, xdbl, xdbl_bf);

    // 4) dt = softplus(dt_r @ dt_proj_w^T + b) -> fp32 (round-5 proven path)
    gemm_dt_f32<<<dim3(16, 32), blk, 0, stream>>>(
        xdbl_bf, dtw_bf, dtb, dt_proj_b);

    // 5) chunked parallel selective scan -> yb (bf16)
    scan_pass1<<<dim3(G_CHUNK, 16), blk, 0, stream>>>(
        dtb, xc_bf, xdbl, A_log, apr, hen);
    scan_pass2<<<dim3(B_SZ * D_STATE * D_INNER / 256), blk, 0, stream>>>(
        apr, hen, H0);
    scan_pass3<<<dim3(G_CHUNK, 16), blk, 0, stream>>>(
        dtb, xc_bf, xz_bf, xdbl, A_log, Dv, H0, yb_bf);

    // 6) out = y @ out_proj_w^T, 128x64 tile, 512 blocks, direct fp32 store
    gemm_out64<<<dim3(16, 32), blk, 0, stream>>>(yb_bf, outw_bf, out);
}

// Round 11
// 370.432 us; speedup vs baseline: 1.6015x; 1.0278x over previous
//
#include <hip/hip_runtime.h>
#include <math.h>

#define D_MODEL 1024
#define D_STATE 16
#define D_CONV  4
#define D_INNER 2048
#define DT_RANK 64
#define B_SZ    2
#define L_SEQ   2048
#define NROW    (B_SZ * L_SEQ)   // 4096

typedef __bf16 bf16x8 __attribute__((ext_vector_type(8)));
typedef float  f32x4  __attribute__((ext_vector_type(4)));
typedef unsigned short ushort8 __attribute__((ext_vector_type(8)));

__device__ __forceinline__ unsigned short f2bf(float f) {
    unsigned u = __float_as_uint(f);
    u += 0x7fff + ((u >> 16) & 1);       // RNE
    return (unsigned short)(u >> 16);
}
__device__ __forceinline__ float bf2f(unsigned short v) {
    return __uint_as_float((unsigned)v << 16);
}
__device__ __forceinline__ float softplus_f(float x) {
    return (x > 20.f) ? x : log1pf(__expf(x));
}

// ---------------------------------------------------------------------------
// Batched fp32 -> bf16 conversion: x, in_proj_w, dt_proj_w, out_proj_w,
// plus x_proj_w padded [96][2048] -> [128][2048].
// ---------------------------------------------------------------------------
#define S_X    (NROW * D_MODEL)                 // 4,194,304
#define S_IN   (2 * D_INNER * D_MODEL)          // 4,194,304
#define S_DT   (D_INNER * DT_RANK)              //   131,072
#define S_OUT  (D_MODEL * D_INNER)              // 2,097,152
#define S_TOT  (S_X + S_IN + S_DT + S_OUT)      // 10,616,832
#define S_PAD  (128 * 2048)                     //   262,144
#define S_ALL  (S_TOT + S_PAD)                  // 10,878,976

__global__ __launch_bounds__(256) void cvt_all(
    const float* __restrict__ x,   const float* __restrict__ inw,
    const float* __restrict__ dtw, const float* __restrict__ outw,
    const float* __restrict__ xpw,
    unsigned short* __restrict__ x_bf,   unsigned short* __restrict__ inw_bf,
    unsigned short* __restrict__ dtw_bf, unsigned short* __restrict__ outw_bf,
    unsigned short* __restrict__ xpw_bf)
{
    const int i = (blockIdx.x * 256 + threadIdx.x) * 4;
    if (i >= S_ALL) return;
    if (i >= S_TOT) {   // padded x_proj_w segment
        const int off = i - S_TOT;
        const int row = off >> 11;
        ushort4 o = make_ushort4(0, 0, 0, 0);
        if (row < 96) {
            const float4 v = *(const float4*)(xpw + (size_t)row * 2048 + (off & 2047));
            o.x = f2bf(v.x); o.y = f2bf(v.y); o.z = f2bf(v.z); o.w = f2bf(v.w);
        }
        *(ushort4*)(xpw_bf + off) = o;
        return;
    }
    const float* src; unsigned short* dst; int off;
    if (i < S_X)                    { src = x;    dst = x_bf;    off = i; }
    else if (i < S_X + S_IN)        { src = inw;  dst = inw_bf;  off = i - S_X; }
    else if (i < S_X + S_IN + S_DT) { src = dtw;  dst = dtw_bf;  off = i - S_X - S_IN; }
    else                            { src = outw; dst = outw_bf; off = i - S_X - S_IN - S_DT; }
    const float4 v = *(const float4*)(src + off);
    ushort4 o;
    o.x = f2bf(v.x); o.y = f2bf(v.y); o.z = f2bf(v.z); o.w = f2bf(v.w);
    *(ushort4*)(dst + off) = o;
}

// ---------------------------------------------------------------------------
// GEMM1 dedicated: xz = x_bf @ inw_bf^T -> bf16 [4096,4096].
// 128x128 tile, BK=64, __launch_bounds__(256,4).
// XCD-region swizzle (1-D grid, bid%8 = XCD under round-robin dispatch):
// XCD R owns by in [R>>2 * 16, +16), bx in [(R&3)*8, +8) -> per-XCD L2
// footprint 4MB A-strip + 2MB B-strip instead of full 12.4MB thrash.
// ---------------------------------------------------------------------------
__global__ __launch_bounds__(256, 4) void gemm_in(
    const unsigned short* __restrict__ A,
    const unsigned short* __restrict__ B,
    unsigned short* __restrict__ Cb)
{
    __shared__ unsigned short As[8][128 * 8];   // 16 KB
    __shared__ unsigned short Bs[8][128 * 8];   // 16 KB

    const int tid  = threadIdx.x;
    const int lane = tid & 63;
    const int w    = tid >> 6;
    const int wr   = w >> 1;
    const int wc   = w & 1;
    const int q    = lane >> 4;
    const int m    = lane & 15;

    const int bid = blockIdx.x;
    const int R   = bid & 7;           // XCD under round-robin dispatch
    const int idx = bid >> 3;          // 0..127 within region
    const int by  = ((R >> 2) << 4) + ((idx >> 3) & 15);   // (R>>2)*16 + 0..15
    const int bx  = ((R & 3) << 3) + (idx & 7);            // (R&3)*8 + 0..7
    const int row0 = by * 128;
    const int col0 = bx * 128;

    f32x4 acc[4][4];
#pragma unroll
    for (int i = 0; i < 4; i++)
#pragma unroll
        for (int j = 0; j < 4; j++) acc[i][j] = (f32x4){0.f, 0.f, 0.f, 0.f};

    for (int k0 = 0; k0 < 1024; k0 += 64) {
#pragma unroll
        for (int i = 0; i < 4; i++) {
            const int c    = w * 4 + i;
            const int kb   = c >> 1;
            const int half = c & 1;
            const unsigned short* ga =
                A + (size_t)(row0 + half * 64 + lane) * 1024 + k0 + kb * 8;
            const unsigned short* gb =
                B + (size_t)(col0 + half * 64 + lane) * 1024 + k0 + kb * 8;
            __builtin_amdgcn_global_load_lds(
                (const __attribute__((address_space(1))) unsigned int*)ga,
                (__attribute__((address_space(3))) unsigned int*)&As[kb][half * 512],
                16, 0, 0);
            __builtin_amdgcn_global_load_lds(
                (const __attribute__((address_space(1))) unsigned int*)gb,
                (__attribute__((address_space(3))) unsigned int*)&Bs[kb][half * 512],
                16, 0, 0);
        }
        __syncthreads();

#pragma unroll
        for (int dep = 0; dep < 2; dep++) {
            bf16x8 af[4], bfr[4];
#pragma unroll
            for (int t = 0; t < 4; t++) {
                af[t]  = *(const bf16x8*)&As[dep * 4 + q][(wr * 64 + t * 16 + m) * 8];
                bfr[t] = *(const bf16x8*)&Bs[dep * 4 + q][(wc * 64 + t * 16 + m) * 8];
            }
#pragma unroll
            for (int mt = 0; mt < 4; mt++)
#pragma unroll
                for (int nt = 0; nt < 4; nt++)
                    acc[mt][nt] = __builtin_amdgcn_mfma_f32_16x16x32_bf16(
                        af[mt], bfr[nt], acc[mt][nt], 0, 0, 0);
        }
        __syncthreads();
    }

    // bf16 epilogue through LDS: two 64-row halves, reuse As
    unsigned short* ep = &As[0][0];
#pragma unroll
    for (int hh = 0; hh < 2; hh++) {
        if (wr == hh) {
#pragma unroll
            for (int mt = 0; mt < 4; mt++)
#pragma unroll
                for (int nt = 0; nt < 4; nt++)
#pragma unroll
                    for (int r = 0; r < 4; r++)
                        ep[(mt * 16 + q * 4 + r) * 128 + wc * 64 + nt * 16 + m] =
                            f2bf(acc[mt][nt][r]);
        }
        __syncthreads();
#pragma unroll
        for (int i = 0; i < 4; i++) {
            const int c    = i * 256 + tid;       // 0..1023
            const int rrow = c >> 4;
            const int off  = (c & 15) * 8;
            *(ushort8*)(Cb + (size_t)(row0 + hh * 64 + rrow) * 4096 + col0 + off) =
                *(const ushort8*)&ep[rrow * 128 + off];
        }
        __syncthreads();
    }
}

// ---------------------------------------------------------------------------
// GEMM4: dt = softplus(dt_r @ dt_proj_w^T + b) -> fp32.
// 128x64 tile -> grid (32,32) = 1024 blocks = 4 blocks/CU. K=64, one iter.
// ---------------------------------------------------------------------------
__global__ __launch_bounds__(256) void gemm_dt_f32(
    const unsigned short* __restrict__ A,   // xdbl_bf [4096][96]
    const unsigned short* __restrict__ B,   // dtw_bf  [2048][64]
    float* __restrict__ C,                  // [4096][2048] fp32
    const float* __restrict__ bias)
{
    __shared__ unsigned short As[8][128 * 8];   // 16 KB
    __shared__ unsigned short Bs[8][64 * 8];    //  8 KB

    const int tid  = threadIdx.x;
    const int lane = tid & 63;
    const int w    = tid >> 6;
    const int wr   = w >> 1;          // 64-row half
    const int wc   = w & 1;           // 32-col half
    const int q    = lane >> 4;
    const int m    = lane & 15;
    const int row0 = blockIdx.y * 128;
    const int col0 = blockIdx.x * 64;

    f32x4 acc[4][2];
#pragma unroll
    for (int i = 0; i < 4; i++)
#pragma unroll
        for (int j = 0; j < 2; j++) acc[i][j] = (f32x4){0.f, 0.f, 0.f, 0.f};

    {
#pragma unroll
        for (int i = 0; i < 4; i++) {
            const int c    = w * 4 + i;
            const int kb   = c >> 1;
            const int half = c & 1;
            const unsigned short* ga =
                A + (size_t)(row0 + half * 64 + lane) * 96 + kb * 8;
            __builtin_amdgcn_global_load_lds(
                (const __attribute__((address_space(1))) unsigned int*)ga,
                (__attribute__((address_space(3))) unsigned int*)&As[kb][half * 512],
                16, 0, 0);
        }
#pragma unroll
        for (int i = 0; i < 2; i++) {
            const int c = w * 2 + i;              // kb 0..7
            const unsigned short* gb =
                B + (size_t)(col0 + lane) * 64 + c * 8;
            __builtin_amdgcn_global_load_lds(
                (const __attribute__((address_space(1))) unsigned int*)gb,
                (__attribute__((address_space(3))) unsigned int*)&Bs[c][0],
                16, 0, 0);
        }
        __syncthreads();

#pragma unroll
        for (int dep = 0; dep < 2; dep++) {
            bf16x8 af[4], bfr[2];
#pragma unroll
            for (int t = 0; t < 4; t++)
                af[t] = *(const bf16x8*)&As[dep * 4 + q][(wr * 64 + t * 16 + m) * 8];
#pragma unroll
            for (int t = 0; t < 2; t++)
                bfr[t] = *(const bf16x8*)&Bs[dep * 4 + q][(wc * 32 + t * 16 + m) * 8];
#pragma unroll
            for (int mt = 0; mt < 4; mt++)
#pragma unroll
                for (int nt = 0; nt < 2; nt++)
                    acc[mt][nt] = __builtin_amdgcn_mfma_f32_16x16x32_bf16(
                        af[mt], bfr[nt], acc[mt][nt], 0, 0, 0);
        }
        __syncthreads();
    }

#pragma unroll
    for (int mt = 0; mt < 4; mt++) {
#pragma unroll
        for (int nt = 0; nt < 2; nt++) {
            const int col = col0 + wc * 32 + nt * 16 + m;
            const float bcol = bias[col];
#pragma unroll
            for (int r = 0; r < 4; r++) {
                const int row = row0 + wr * 64 + mt * 16 + q * 4 + r;
                C[(size_t)row * D_INNER + col] = softplus_f(acc[mt][nt][r] + bcol);
            }
        }
    }
}

// ---------------------------------------------------------------------------
// GEMM6: out = y @ out_proj_w^T, 128x64 tile (512 blocks), direct fp32 stores.
// ---------------------------------------------------------------------------
__global__ __launch_bounds__(256) void gemm_out64(
    const unsigned short* __restrict__ A,   // yb [4096][2048]
    const unsigned short* __restrict__ B,   // outw [1024][2048]
    float* __restrict__ out)                // [4096][1024]
{
    __shared__ unsigned short As[8][128 * 8];   // 16 KB
    __shared__ unsigned short Bs[8][64 * 8];    //  8 KB

    const int tid  = threadIdx.x;
    const int lane = tid & 63;
    const int w    = tid >> 6;
    const int wr   = w >> 1;
    const int wc   = w & 1;
    const int q    = lane >> 4;
    const int m    = lane & 15;
    const int row0 = blockIdx.y * 128;
    const int col0 = blockIdx.x * 64;

    f32x4 acc[4][2];
#pragma unroll
    for (int i = 0; i < 4; i++)
#pragma unroll
        for (int j = 0; j < 2; j++) acc[i][j] = (f32x4){0.f, 0.f, 0.f, 0.f};

    for (int k0 = 0; k0 < 2048; k0 += 64) {
#pragma unroll
        for (int i = 0; i < 4; i++) {
            const int c    = w * 4 + i;
            const int kb   = c >> 1;
            const int half = c & 1;
            const unsigned short* ga =
                A + (size_t)(row0 + half * 64 + lane) * 2048 + k0 + kb * 8;
            __builtin_amdgcn_global_load_lds(
                (const __attribute__((address_space(1))) unsigned int*)ga,
                (__attribute__((address_space(3))) unsigned int*)&As[kb][half * 512],
                16, 0, 0);
        }
#pragma unroll
        for (int i = 0; i < 2; i++) {
            const int c = w * 2 + i;              // kb 0..7
            const unsigned short* gb =
                B + (size_t)(col0 + lane) * 2048 + k0 + c * 8;
            __builtin_amdgcn_global_load_lds(
                (const __attribute__((address_space(1))) unsigned int*)gb,
                (__attribute__((address_space(3))) unsigned int*)&Bs[c][0],
                16, 0, 0);
        }
        __syncthreads();

#pragma unroll
        for (int dep = 0; dep < 2; dep++) {
            bf16x8 af[4], bfr[2];
#pragma unroll
            for (int t = 0; t < 4; t++)
                af[t] = *(const bf16x8*)&As[dep * 4 + q][(wr * 64 + t * 16 + m) * 8];
#pragma unroll
            for (int t = 0; t < 2; t++)
                bfr[t] = *(const bf16x8*)&Bs[dep * 4 + q][(wc * 32 + t * 16 + m) * 8];
#pragma unroll
            for (int mt = 0; mt < 4; mt++)
#pragma unroll
                for (int nt = 0; nt < 2; nt++)
                    acc[mt][nt] = __builtin_amdgcn_mfma_f32_16x16x32_bf16(
                        af[mt], bfr[nt], acc[mt][nt], 0, 0, 0);
        }
        __syncthreads();
    }

#pragma unroll
    for (int mt = 0; mt < 4; mt++) {
#pragma unroll
        for (int nt = 0; nt < 2; nt++) {
            const int col = col0 + wc * 32 + nt * 16 + m;
#pragma unroll
            for (int r = 0; r < 4; r++) {
                const int row = row0 + wr * 64 + mt * 16 + q * 4 + r;
                out[(size_t)row * D_MODEL + col] = acc[mt][nt][r];
            }
        }
    }
}

// ---------------------------------------------------------------------------
// GEMM3 bf16 split-K: x_dbl = xc_bf[4096,2048] @ xpw_pad[128,2048]^T.
// ---------------------------------------------------------------------------
#define G3Z 8

__global__ __launch_bounds__(256) void gemm3_bf16_splitk(
    const unsigned short* __restrict__ A,   // [4096][2048]
    const unsigned short* __restrict__ B,   // [128][2048] padded
    float* __restrict__ Cp)                 // [G3Z][4096][96]
{
    __shared__ unsigned short As[8][128 * 8];
    __shared__ unsigned short Bs[8][128 * 8];

    const int tid  = threadIdx.x;
    const int lane = tid & 63;
    const int w    = tid >> 6;
    const int wr   = w >> 1;
    const int wc   = w & 1;
    const int q    = lane >> 4;
    const int m    = lane & 15;
    const int row0 = blockIdx.y * 128;
    const int kz0  = blockIdx.z * (2048 / G3Z);

    f32x4 acc[4][4];
#pragma unroll
    for (int i = 0; i < 4; i++)
#pragma unroll
        for (int j = 0; j < 4; j++) acc[i][j] = (f32x4){0.f, 0.f, 0.f, 0.f};

    for (int k0 = kz0; k0 < kz0 + (2048 / G3Z); k0 += 64) {
#pragma unroll
        for (int i = 0; i < 4; i++) {
            const int c    = w * 4 + i;
            const int kb   = c >> 1;
            const int half = c & 1;
            const unsigned short* ga =
                A + (size_t)(row0 + half * 64 + lane) * 2048 + k0 + kb * 8;
            const unsigned short* gb =
                B + (size_t)(half * 64 + lane) * 2048 + k0 + kb * 8;
            __builtin_amdgcn_global_load_lds(
                (const __attribute__((address_space(1))) unsigned int*)ga,
                (__attribute__((address_space(3))) unsigned int*)&As[kb][half * 512],
                16, 0, 0);
            __builtin_amdgcn_global_load_lds(
                (const __attribute__((address_space(1))) unsigned int*)gb,
                (__attribute__((address_space(3))) unsigned int*)&Bs[kb][half * 512],
                16, 0, 0);
        }
        __syncthreads();

#pragma unroll
        for (int dep = 0; dep < 2; dep++) {
            bf16x8 af[4], bfr[4];
#pragma unroll
            for (int t = 0; t < 4; t++) {
                af[t]  = *(const bf16x8*)&As[dep * 4 + q][(wr * 64 + t * 16 + m) * 8];
                bfr[t] = *(const bf16x8*)&Bs[dep * 4 + q][(wc * 64 + t * 16 + m) * 8];
            }
#pragma unroll
            for (int mt = 0; mt < 4; mt++)
#pragma unroll
                for (int nt = 0; nt < 4; nt++)
                    acc[mt][nt] = __builtin_amdgcn_mfma_f32_16x16x32_bf16(
                        af[mt], bfr[nt], acc[mt][nt], 0, 0, 0);
        }
        __syncthreads();
    }

    float* Cz = Cp + (size_t)blockIdx.z * NROW * 96;
#pragma unroll
    for (int mt = 0; mt < 4; mt++) {
#pragma unroll
        for (int nt = 0; nt < 4; nt++) {
            const int col = wc * 64 + nt * 16 + m;
            if (col < 96) {
#pragma unroll
                for (int r = 0; r < 4; r++) {
                    const int row = row0 + wr * 64 + mt * 16 + q * 4 + r;
                    Cz[(size_t)row * 96 + col] = acc[mt][nt][r];
                }
            }
        }
    }
}

__global__ __launch_bounds__(256) void reduce3(
    const float* __restrict__ Cp,
    float* __restrict__ xdbl,
    unsigned short* __restrict__ xdbl_bf)
{
    const int idx = blockIdx.x * 256 + threadIdx.x;   // < 4096*96
    float s = 0.f;
#pragma unroll
    for (int z = 0; z < G3Z; z++)
        s += Cp[(size_t)z * NROW * 96 + idx];
    xdbl[idx] = s;
    xdbl_bf[idx] = f2bf(s);
}

// ---------------------------------------------------------------------------
// Causal depthwise conv1d (K=4, left-pad 3) + bias + SiLU, 8 channels/thread.
// ---------------------------------------------------------------------------
__global__ __launch_bounds__(256) void conv_silu8(
    const unsigned short* __restrict__ xz,   // [NROW][2*D_INNER] bf16
    const float* __restrict__ conv_w,        // [D_INNER][4]
    const float* __restrict__ conv_b,
    unsigned short* __restrict__ xc_bf)      // [NROW][D_INNER] bf16
{
    const int i8 = (blockIdx.x * 256 + threadIdx.x) * 8;  // over NROW*D_INNER
    const int d0 = i8 & (D_INNER - 1);
    const int rt = i8 >> 11;
    const int t  = rt & (L_SEQ - 1);

    const unsigned short* base = xz + (size_t)rt * (2 * D_INNER) + d0;
    ushort8 v0, v1, v2, v3;
    v3 = *(const ushort8*)(base);
    v2 = (t >= 1) ? *(const ushort8*)(base - 1 * 2 * D_INNER) : (ushort8)0;
    v1 = (t >= 2) ? *(const ushort8*)(base - 2 * 2 * D_INNER) : (ushort8)0;
    v0 = (t >= 3) ? *(const ushort8*)(base - 3 * 2 * D_INNER) : (ushort8)0;

    ushort8 o;
#pragma unroll
    for (int j = 0; j < 8; j++) {
        const float4 wv = *(const float4*)(conv_w + (d0 + j) * 4);
        float acc = conv_b[d0 + j];
        acc = fmaf(wv.x, bf2f(v0[j]), acc);
        acc = fmaf(wv.y, bf2f(v1[j]), acc);
        acc = fmaf(wv.z, bf2f(v2[j]), acc);
        acc = fmaf(wv.w, bf2f(v3[j]), acc);
        const float sig = 1.f / (1.f + __expf(-acc));
        o[j] = f2bf(acc * sig);
    }
    *(ushort8*)(xc_bf + i8) = o;
}

// ---------------------------------------------------------------------------
// Chunked parallel selective scan, thread-per-d with h[16] in registers.
// G_CHUNK=64 -> grid (64,16) = 1024 blocks = 4 blocks/CU for latency hiding.
// ---------------------------------------------------------------------------
#define G_CHUNK 64
#define T_CHUNK (L_SEQ / G_CHUNK)   // 32

__global__ __launch_bounds__(256) void scan_pass1(
    const float* __restrict__ dtbuf,            // [NROW][D_INNER] fp32
    const unsigned short* __restrict__ xc,      // [NROW][D_INNER] bf16
    const float* __restrict__ xdbl,             // [NROW][96]
    const float* __restrict__ A_log,            // [D_INNER][16]
    float* __restrict__ aprod,                  // [G][B][16][D_INNER]
    float* __restrict__ hend)
{
    __shared__ float B_s[T_CHUNK][16];

    const int tid = threadIdx.x;
    const int g   = blockIdx.x;
    const int db  = blockIdx.y;
    const int b   = db >> 3;
    const int d   = (db & 7) * 256 + tid;
    const size_t rowbase = (size_t)b * L_SEQ + (size_t)g * T_CHUNK;

    if (tid < T_CHUNK * 4) {
        const int tt = tid >> 2, q4 = (tid & 3) * 4;
        *(float4*)&B_s[tt][q4] =
            *(const float4*)&xdbl[(rowbase + tt) * 96 + DT_RANK + q4];
    }

    float A_dn[16];
#pragma unroll
    for (int n = 0; n < 16; n++)
        A_dn[n] = -expf(A_log[(size_t)d * D_STATE + n]);

    float h[16], ap[16];
#pragma unroll
    for (int n = 0; n < 16; n++) { h[n] = 0.f; ap[n] = 1.f; }

    __syncthreads();

#pragma unroll 2
    for (int t = 0; t < T_CHUNK; t++) {
        const size_t r = rowbase + t;
        const float dtv = dtbuf[r * D_INNER + d];
        const float xv  = bf2f(xc[r * D_INNER + d]);
        const float dtx = dtv * xv;
        float Bv[16];
        *(float4*)&Bv[0]  = *(const float4*)&B_s[t][0];
        *(float4*)&Bv[4]  = *(const float4*)&B_s[t][4];
        *(float4*)&Bv[8]  = *(const float4*)&B_s[t][8];
        *(float4*)&Bv[12] = *(const float4*)&B_s[t][12];
#pragma unroll
        for (int n = 0; n < 16; n++) {
            const float dA = __expf(dtv * A_dn[n]);
            ap[n] *= dA;
            h[n] = fmaf(dA, h[n], dtx * Bv[n]);
        }
    }

    const size_t base = ((size_t)g * B_SZ + b) * D_STATE * D_INNER + d;
#pragma unroll
    for (int n = 0; n < 16; n++) {
        aprod[base + (size_t)n * D_INNER] = ap[n];
        hend[base + (size_t)n * D_INNER]  = h[n];
    }
}

__global__ __launch_bounds__(256) void scan_pass2(
    const float* __restrict__ aprod,
    const float* __restrict__ hend,
    float* __restrict__ H0)
{
    const int idx = blockIdx.x * 256 + threadIdx.x;
    const size_t stride = (size_t)B_SZ * D_STATE * D_INNER;
    float h = 0.f;
#pragma unroll 8
    for (int g = 0; g < G_CHUNK; g++) {
        H0[(size_t)g * stride + idx] = h;
        h = fmaf(aprod[(size_t)g * stride + idx], h, hend[(size_t)g * stride + idx]);
    }
}

__global__ __launch_bounds__(256) void scan_pass3(
    const float* __restrict__ dtbuf,           // fp32
    const unsigned short* __restrict__ xc,     // bf16
    const unsigned short* __restrict__ xz,     // bf16, z at +D_INNER
    const float* __restrict__ xdbl,
    const float* __restrict__ A_log,
    const float* __restrict__ Dvec,
    const float* __restrict__ H0,
    unsigned short* __restrict__ y)            // bf16
{
    __shared__ float B_s[T_CHUNK][16];
    __shared__ float C_s[T_CHUNK][16];

    const int tid = threadIdx.x;
    const int g   = blockIdx.x;
    const int db  = blockIdx.y;
    const int b   = db >> 3;
    const int d   = (db & 7) * 256 + tid;
    const size_t rowbase = (size_t)b * L_SEQ + (size_t)g * T_CHUNK;

    if (tid < T_CHUNK * 4) {
        const int tt = tid >> 2, q4 = (tid & 3) * 4;
        *(float4*)&B_s[tt][q4] =
            *(const float4*)&xdbl[(rowbase + tt) * 96 + DT_RANK + q4];
        *(float4*)&C_s[tt][q4] =
            *(const float4*)&xdbl[(rowbase + tt) * 96 + DT_RANK + D_STATE + q4];
    }

    float A_dn[16];
#pragma unroll
    for (int n = 0; n < 16; n++)
        A_dn[n] = -expf(A_log[(size_t)d * D_STATE + n]);
    const float D_d = Dvec[d];

    float h[16];
    const size_t base = ((size_t)g * B_SZ + b) * D_STATE * D_INNER + d;
#pragma unroll
    for (int n = 0; n < 16; n++)
        h[n] = H0[base + (size_t)n * D_INNER];

    __syncthreads();

#pragma unroll 2
    for (int t = 0; t < T_CHUNK; t++) {
        const size_t r = rowbase + t;
        const float dtv = dtbuf[r * D_INNER + d];
        const float xv  = bf2f(xc[r * D_INNER + d]);
        const float zv  = bf2f(xz[r * (2 * D_INNER) + D_INNER + d]);
        const float dtx = dtv * xv;
        float Bv[16], Cv[16];
        *(float4*)&Bv[0]  = *(const float4*)&B_s[t][0];
        *(float4*)&Bv[4]  = *(const float4*)&B_s[t][4];
        *(float4*)&Bv[8]  = *(const float4*)&B_s[t][8];
        *(float4*)&Bv[12] = *(const float4*)&B_s[t][12];
        *(float4*)&Cv[0]  = *(const float4*)&C_s[t][0];
        *(float4*)&Cv[4]  = *(const float4*)&C_s[t][4];
        *(float4*)&Cv[8]  = *(const float4*)&C_s[t][8];
        *(float4*)&Cv[12] = *(const float4*)&C_s[t][12];
        float dot = 0.f;
#pragma unroll
        for (int n = 0; n < 16; n++) {
            const float dA = __expf(dtv * A_dn[n]);
            h[n] = fmaf(dA, h[n], dtx * Bv[n]);
            dot = fmaf(h[n], Cv[n], dot);
        }
        const float sig = 1.f / (1.f + __expf(-zv));
        const float yv = (dot + D_d * xv) * (zv * sig);
        y[r * D_INNER + d] = f2bf(yv);
    }
}

// ---------------------------------------------------------------------------
extern "C" void kernel_launch(void* const* d_in, const int* in_sizes, int n_in,
                              void* d_out, int out_size, void* d_ws, size_t ws_size,
                              hipStream_t stream) {
    const float* x          = (const float*)d_in[0];
    const float* in_proj_w  = (const float*)d_in[1];
    const float* conv_w     = (const float*)d_in[2];
    const float* conv_b     = (const float*)d_in[3];
    const float* x_proj_w   = (const float*)d_in[4];
    const float* dt_proj_w  = (const float*)d_in[5];
    const float* dt_proj_b  = (const float*)d_in[6];
    const float* A_log      = (const float*)d_in[7];
    const float* Dv         = (const float*)d_in[8];
    const float* out_proj_w = (const float*)d_in[9];
    float* out = (float*)d_out;

    const size_t SST = (size_t)G_CHUNK * B_SZ * D_STATE * D_INNER;  // 4,194,304

    float* ws = (float*)d_ws;
    float* xdbl = ws;                                   //   393,216 f
    float* apr  = xdbl + (size_t)393216;                // 4,194,304 f
    float* hen  = apr  + SST;                           // 4,194,304 f
    float* H0   = hen  + SST;                           // 4,194,304 f
    float* Cp3  = H0   + SST;                           // 3,145,728 f
    float* dtb  = Cp3  + (size_t)3145728;               // 8,388,608 f (fp32 dt)
    unsigned short* xz_bf   = (unsigned short*)(dtb + 8388608);  // 16,777,216 us
    unsigned short* xc_bf   = xz_bf   + (size_t)16777216;        //  8,388,608 us
    unsigned short* yb_bf   = xc_bf   + (size_t)8388608;         //  8,388,608 us
    unsigned short* x_bf    = yb_bf   + (size_t)8388608;         //  4,194,304 us
    unsigned short* inw_bf  = x_bf    + (size_t)4194304;         //  4,194,304 us
    unsigned short* dtw_bf  = inw_bf  + (size_t)4194304;         //    131,072 us
    unsigned short* outw_bf = dtw_bf  + (size_t)131072;          //  2,097,152 us
    unsigned short* xpw_bf  = outw_bf + (size_t)2097152;         //    262,144 us
    unsigned short* xdbl_bf = xpw_bf  + (size_t)262144;          //    393,216 us

    dim3 blk(256);

    // 0) all fp32->bf16 conversions (single launch)
    cvt_all<<<dim3(S_ALL / 1024), blk, 0, stream>>>(
        x, in_proj_w, dt_proj_w, out_proj_w, x_proj_w,
        x_bf, inw_bf, dtw_bf, outw_bf, xpw_bf);

    // 1) xz = x @ in_proj_w^T   (M=4096, N=4096, K=1024) -> bf16, XCD swizzle
    gemm_in<<<dim3(1024), blk, 0, stream>>>(x_bf, inw_bf, xz_bf);

    // 2) conv + bias + SiLU -> xc_bf (8 channels/thread)
    conv_silu8<<<dim3((NROW * D_INNER) / (256 * 8)), blk, 0, stream>>>(
        xz_bf, conv_w, conv_b, xc_bf);

    // 3) x_dbl = xc @ x_proj_w^T (split-K bf16)
    gemm3_bf16_splitk<<<dim3(1, 32, G3Z), blk, 0, stream>>>(xc_bf, xpw_bf, Cp3);
    reduce3<<<dim3((NROW * 96) / 256), blk, 0, stream>>>(Cp3, xdbl, xdbl_bf);

    // 4) dt = softplus(dt_r @ dt_proj_w^T + b) -> fp32, 128x64 tile 1024 blks
    gemm_dt_f32<<<dim3(32, 32), blk, 0, stream>>>(
        xdbl_bf, dtw_bf, dtb, dt_proj_b);

    // 5) chunked parallel selective scan -> yb (bf16), 1024 blocks/pass
    scan_pass1<<<dim3(G_CHUNK, 16), blk, 0, stream>>>(
        dtb, xc_bf, xdbl, A_log, apr, hen);
    scan_pass2<<<dim3(B_SZ * D_STATE * D_INNER / 256), blk, 0, stream>>>(
        apr, hen, H0);
    scan_pass3<<<dim3(G_CHUNK, 16), blk, 0, stream>>>(
        dtb, xc_bf, xz_bf, xdbl, A_log, Dv, H0, yb_bf);

    // 6) out = y @ out_proj_w^T, 128x64 tile, 512 blocks, direct fp32 store
    gemm_out64<<<dim3(16, 32), blk, 0, stream>>>(yb_bf, outw_bf, out);
}